// Round 4
// baseline (104.833 us; speedup 1.0000x reference)
//
#include <hip/hip_runtime.h>
#include <math.h>

#define WIDTH    1024
#define NCOLS    8193        // N + 1 (bias in last column)
#define N_LAYERS 8
#define NBLOCKS  256
#define TPB      256
#define TAGW     0x5F3759DFu

typedef __attribute__((ext_vector_type(4))) float        f32x4;
typedef __attribute__((ext_vector_type(4))) unsigned int u32x4;

// ---- weights (cached) + bias, self-contained wait (layer 1) ----
__device__ __forceinline__ void ld_w_wait(const float* wp, const float* bp,
        f32x4& w0, f32x4& w1, f32x4& w2, f32x4& w3, float& bi)
{
    asm volatile(
        "global_load_dwordx4 %0, %5, off\n\t"
        "global_load_dwordx4 %1, %5, off offset:16\n\t"
        "global_load_dwordx4 %2, %5, off offset:32\n\t"
        "global_load_dwordx4 %3, %5, off offset:48\n\t"
        "global_load_dword   %4, %6, off\n\t"
        "s_waitcnt vmcnt(0)"
        : "=v"(w0), "=v"(w1), "=v"(w2), "=v"(w3), "=v"(bi)
        : "v"(wp), "v"(bp)
        : "memory");
}

// ---- combined: weights+bias (cached) + 16 tagged slots (coherent), wait all ----
__device__ __forceinline__ void ld_first(const float* wp, const float* bp,
        const unsigned long long* sp,
        f32x4& w0, f32x4& w1, f32x4& w2, f32x4& w3, float& bi,
        u32x4& a0, u32x4& a1, u32x4& a2, u32x4& a3,
        u32x4& a4, u32x4& a5, u32x4& a6, u32x4& a7)
{
    asm volatile(
        "global_load_dwordx4 %0, %13, off\n\t"
        "global_load_dwordx4 %1, %13, off offset:16\n\t"
        "global_load_dwordx4 %2, %13, off offset:32\n\t"
        "global_load_dwordx4 %3, %13, off offset:48\n\t"
        "global_load_dword   %4, %14, off\n\t"
        "global_load_dwordx4 %5, %15, off sc0 sc1\n\t"
        "global_load_dwordx4 %6, %15, off offset:16 sc0 sc1\n\t"
        "global_load_dwordx4 %7, %15, off offset:32 sc0 sc1\n\t"
        "global_load_dwordx4 %8, %15, off offset:48 sc0 sc1\n\t"
        "global_load_dwordx4 %9, %15, off offset:64 sc0 sc1\n\t"
        "global_load_dwordx4 %10, %15, off offset:80 sc0 sc1\n\t"
        "global_load_dwordx4 %11, %15, off offset:96 sc0 sc1\n\t"
        "global_load_dwordx4 %12, %15, off offset:112 sc0 sc1\n\t"
        "s_waitcnt vmcnt(0)"
        : "=v"(w0), "=v"(w1), "=v"(w2), "=v"(w3), "=v"(bi),
          "=v"(a0), "=v"(a1), "=v"(a2), "=v"(a3),
          "=v"(a4), "=v"(a5), "=v"(a6), "=v"(a7)
        : "v"(wp), "v"(bp), "v"(sp)
        : "memory");
}

// ---- re-poll the 16 slots only ----
__device__ __forceinline__ void ld_poll(const unsigned long long* sp,
        u32x4& a0, u32x4& a1, u32x4& a2, u32x4& a3,
        u32x4& a4, u32x4& a5, u32x4& a6, u32x4& a7)
{
    asm volatile(
        "global_load_dwordx4 %0, %8, off sc0 sc1\n\t"
        "global_load_dwordx4 %1, %8, off offset:16 sc0 sc1\n\t"
        "global_load_dwordx4 %2, %8, off offset:32 sc0 sc1\n\t"
        "global_load_dwordx4 %3, %8, off offset:48 sc0 sc1\n\t"
        "global_load_dwordx4 %4, %8, off offset:64 sc0 sc1\n\t"
        "global_load_dwordx4 %5, %8, off offset:80 sc0 sc1\n\t"
        "global_load_dwordx4 %6, %8, off offset:96 sc0 sc1\n\t"
        "global_load_dwordx4 %7, %8, off offset:112 sc0 sc1\n\t"
        "s_waitcnt vmcnt(0)"
        : "=v"(a0), "=v"(a1), "=v"(a2), "=v"(a3),
          "=v"(a4), "=v"(a5), "=v"(a6), "=v"(a7)
        : "v"(sp)
        : "memory");
}

// ---- coherent 8B tagged store (value | TAG) ----
__device__ __forceinline__ void st_slot(unsigned long long* p, float h)
{
    unsigned long long pk = ((unsigned long long)TAGW << 32)
                          | (unsigned long long)__float_as_uint(h);
    asm volatile("global_store_dwordx2 %0, %1, off sc0 sc1"
                 :: "v"(p), "v"(pk) : "memory");
}

__device__ __forceinline__ bool tags_ok(const u32x4 a[8])
{
    bool ok = true;
    #pragma unroll
    for (int i = 0; i < 8; ++i)
        ok &= (a[i].y == TAGW) & (a[i].w == TAGW);
    return ok;
}

__device__ __forceinline__ float dot16(const f32x4 w[4], const u32x4 a[8])
{
    float s = 0.f;
    #pragma unroll
    for (int j = 0; j < 8; ++j) {
        const int e0 = 2 * j, e1 = 2 * j + 1;
        s += w[e0 >> 2][e0 & 3] * __uint_as_float(a[j].x);
        s += w[e1 >> 2][e1 & 3] * __uint_as_float(a[j].z);
    }
    return s;
}

// Fused 7-layer MLP; dataflow sync via tagged coherent slots. 1024 waves, 1 row/wave.
__global__ __launch_bounds__(TPB) void mlp_fused_kernel(
    const float* __restrict__ P,               // (8192 x 8193)
    const float* __restrict__ x,               // (1024,)
    float* __restrict__ out,                   // (1024,)
    unsigned long long* __restrict__ slots)    // 6 x 1024 tagged slots (zeroed)
{
    const int wid  = threadIdx.x >> 6;
    const int lane = threadIdx.x & 63;
    const int row  = blockIdx.x * (TPB / 64) + wid;   // 0..1023

    // ---------------- layer 1: read x directly ----------------
    {
        const size_t rb = (size_t)(WIDTH + row) * (size_t)NCOLS;   // l = 1
        f32x4 w[4]; float bi;
        ld_w_wait(P + rb + lane * 16, P + rb + (NCOLS - 1),
                  w[0], w[1], w[2], w[3], bi);
        const f32x4* xv = (const f32x4*)x + lane * 4;   // x is 16B-aligned
        float s = 0.f;
        #pragma unroll
        for (int j = 0; j < 4; ++j) {
            f32x4 xj = xv[j];
            s += w[j].x * xj.x + w[j].y * xj.y + w[j].z * xj.z + w[j].w * xj.w;
        }
        #pragma unroll
        for (int off = 32; off > 0; off >>= 1) s += __shfl_xor(s, off, 64);
        float aff = s + bi;
        float h = aff / (1.f + __expf(-aff));           // silu
        if (lane == 0) st_slot(slots + row, h);
    }

    // ---------------- layers 2..7 ----------------
    #pragma unroll
    for (int l = 2; l < N_LAYERS; ++l) {
        const bool last = (l == N_LAYERS - 1);
        const size_t rb = (size_t)(l * WIDTH + row) * (size_t)NCOLS;
        const float* wp = P + rb + (size_t)(l - 1) * WIDTH + lane * 16;
        const float* bp = P + rb + (NCOLS - 1);
        const unsigned long long* sp = slots + (size_t)(l - 2) * WIDTH + lane * 16;

        f32x4 w[4]; float bi; u32x4 a[8];
        ld_first(wp, bp, sp, w[0], w[1], w[2], w[3], bi,
                 a[0], a[1], a[2], a[3], a[4], a[5], a[6], a[7]);
        while (!__all(tags_ok(a)))
            ld_poll(sp, a[0], a[1], a[2], a[3], a[4], a[5], a[6], a[7]);

        float s = dot16(w, a);
        #pragma unroll
        for (int off = 32; off > 0; off >>= 1) s += __shfl_xor(s, off, 64);
        float aff = s + bi;
        float h = last ? aff : aff / (1.f + __expf(-aff));

        if (lane == 0) {
            if (last) out[row] = h;
            else      st_slot(slots + (size_t)(l - 1) * WIDTH + row, h);
        }
    }
}

extern "C" void kernel_launch(void* const* d_in, const int* in_sizes, int n_in,
                              void* d_out, int out_size, void* d_ws, size_t ws_size,
                              hipStream_t stream) {
    const float* x = (const float*)d_in[0];   // (1024,)
    const float* P = (const float*)d_in[1];   // (8192, 8193)
    float* out = (float*)d_out;               // (1024,)
    unsigned long long* slots = (unsigned long long*)d_ws;   // 6*1024 slots

    // clear tags (graph node, ordered before the kernel on this stream)
    hipMemsetAsync(slots, 0, (N_LAYERS - 2) * WIDTH * sizeof(unsigned long long),
                   stream);

    void* args[] = { (void*)&P, (void*)&x, (void*)&out, (void*)&slots };
    hipLaunchCooperativeKernel((const void*)mlp_fused_kernel,
                               dim3(NBLOCKS), dim3(TPB), args, 0, stream);
}

// Round 6
// 51.369 us; speedup vs baseline: 2.0408x; 2.0408x over previous
//
#include <hip/hip_runtime.h>
#include <math.h>

#define WIDTH    1024
#define NCOLS    8193        // N + 1 (bias in last column)
#define N_LAYERS 8
#define NBLOCKS  64
#define TPB      1024
#define WPB      (TPB / 64)  // 16 waves -> 16 rows per block

typedef __attribute__((ext_vector_type(4))) float f32x4;

// weights (cached path) + bias, explicit in-statement wait.
// Early-clobber on ALL outputs: prevents RA overlapping an output tuple with
// the address pairs (async load retirement would clobber them -> R5 crash).
__device__ __forceinline__ void ld_w_wait(const float* wp, const float* bp,
        f32x4& w0, f32x4& w1, f32x4& w2, f32x4& w3, float& bi)
{
    asm volatile(
        "global_load_dwordx4 %0, %5, off\n\t"
        "global_load_dwordx4 %1, %5, off offset:16\n\t"
        "global_load_dwordx4 %2, %5, off offset:32\n\t"
        "global_load_dwordx4 %3, %5, off offset:48\n\t"
        "global_load_dword   %4, %6, off\n\t"
        "s_waitcnt vmcnt(0)"
        : "=&v"(w0), "=&v"(w1), "=&v"(w2), "=&v"(w3), "=&v"(bi)
        : "v"(wp), "v"(bp)
        : "memory");
}

// activation bulk read: 64B/lane, L1/L2-bypass (coherent), wait all
__device__ __forceinline__ void ld_act(const float* ap,
        f32x4& a0, f32x4& a1, f32x4& a2, f32x4& a3)
{
    asm volatile(
        "global_load_dwordx4 %0, %4, off sc0 sc1\n\t"
        "global_load_dwordx4 %1, %4, off offset:16 sc0 sc1\n\t"
        "global_load_dwordx4 %2, %4, off offset:32 sc0 sc1\n\t"
        "global_load_dwordx4 %3, %4, off offset:48 sc0 sc1\n\t"
        "s_waitcnt vmcnt(0)"
        : "=&v"(a0), "=&v"(a1), "=&v"(a2), "=&v"(a3)
        : "v"(ap)
        : "memory");
}

// coherent 4B stores (write-through to the coherence point, no dirty copy)
__device__ __forceinline__ void st_act(float* p, float v)
{
    asm volatile("global_store_dword %0, %1, off sc0 sc1"
                 :: "v"(p), "v"(v) : "memory");
}
__device__ __forceinline__ void st_flag(unsigned* p, unsigned v)
{
    asm volatile("global_store_dword %0, %1, off sc0 sc1"
                 :: "v"(p), "v"(v) : "memory");
}
// coherent 4B flag load
__device__ __forceinline__ unsigned ld_flag(const unsigned* p)
{
    unsigned v;
    asm volatile("global_load_dword %0, %1, off sc0 sc1\n\t"
                 "s_waitcnt vmcnt(0)"
                 : "=&v"(v) : "v"(p) : "memory");
    return v;
}

__device__ __forceinline__ float dot_wa(const f32x4 w[4], const f32x4 a[4])
{
    float s = 0.f;
    #pragma unroll
    for (int j = 0; j < 4; ++j)
        s += w[j].x * a[j].x + w[j].y * a[j].y
           + w[j].z * a[j].z + w[j].w * a[j].w;
    return s;
}

// Fused 7-layer MLP. Inter-layer sync: per-block coherent flags, zero fences.
// 64 blocks x 1024 threads = 1024 waves; wave g owns row g each layer.
__global__ __launch_bounds__(TPB) void mlp_fused_kernel(
    const float* __restrict__ P,          // (8192 x 8193)
    const float* __restrict__ x,          // (1024,)
    float* __restrict__ out,              // (1024,)
    float* __restrict__ slots,            // 6 x 1024 activation floats
    unsigned* __restrict__ flags)         // 8 x 64 flags, zeroed before launch
{
    const int wid  = threadIdx.x >> 6;
    const int lane = threadIdx.x & 63;
    const int bid  = blockIdx.x;
    const int row  = bid * WPB + wid;     // 0..1023

    // ---------------- layer 1: read x directly ----------------
    {
        const size_t rb = (size_t)(WIDTH + row) * (size_t)NCOLS;
        f32x4 w[4]; float bi;
        ld_w_wait(P + rb + lane * 16, P + rb + (NCOLS - 1),
                  w[0], w[1], w[2], w[3], bi);
        const f32x4* xv = (const f32x4*)x + lane * 4;   // x is 16B-aligned
        f32x4 a[4];
        #pragma unroll
        for (int j = 0; j < 4; ++j) a[j] = xv[j];
        float s = dot_wa(w, a);
        #pragma unroll
        for (int off = 32; off > 0; off >>= 1) s += __shfl_xor(s, off, 64);
        float aff = s + bi;
        float h = aff / (1.f + __expf(-aff));            // silu
        if (lane == 0) st_act(slots + row, h);
        asm volatile("s_waitcnt vmcnt(0)" ::: "memory"); // act committed
        __syncthreads();                                  // whole block committed
    }

    // ---------------- layers 2..7 ----------------
    #pragma unroll
    for (int l = 2; l < N_LAYERS; ++l) {
        const bool last = (l == N_LAYERS - 1);

        // arrive: this block's layer-(l-1) activations are all committed
        if (threadIdx.x == 0)
            st_flag(flags + (l - 1) * NBLOCKS + bid, 1u);

        // overlap the barrier window with this layer's weight loads (cached)
        const size_t rb = (size_t)(l * WIDTH + row) * (size_t)NCOLS;
        f32x4 w[4]; float bi;
        ld_w_wait(P + rb + (size_t)(l - 1) * WIDTH + lane * 16,
                  P + rb + (NCOLS - 1), w[0], w[1], w[2], w[3], bi);

        // wave 0 polls all 64 block-flags: 1 lane per block, 1 load per round
        if (threadIdx.x < 64) {
            const unsigned* fp = flags + (l - 1) * NBLOCKS + lane;
            while (!__all(ld_flag(fp) == 1u)) { /* spin */ }
        }
        __syncthreads();

        // bulk-read previous activations (coherent, one shot)
        f32x4 a[4];
        ld_act(slots + (size_t)(l - 2) * WIDTH + lane * 16,
               a[0], a[1], a[2], a[3]);

        float s = dot_wa(w, a);
        #pragma unroll
        for (int off = 32; off > 0; off >>= 1) s += __shfl_xor(s, off, 64);
        float aff = s + bi;
        float h = last ? aff : aff / (1.f + __expf(-aff));

        if (lane == 0) {
            if (last) out[row] = h;      // plain store; end-of-kernel flush
            else      st_act(slots + (size_t)(l - 1) * WIDTH + row, h);
        }
        if (!last) {
            asm volatile("s_waitcnt vmcnt(0)" ::: "memory");
            __syncthreads();
        }
    }
}

extern "C" void kernel_launch(void* const* d_in, const int* in_sizes, int n_in,
                              void* d_out, int out_size, void* d_ws, size_t ws_size,
                              hipStream_t stream) {
    const float* x = (const float*)d_in[0];   // (1024,)
    const float* P = (const float*)d_in[1];   // (8192, 8193)
    float* out = (float*)d_out;               // (1024,)

    float* slots = (float*)d_ws;                                    // 6*1024 f32
    unsigned* flags = (unsigned*)((char*)d_ws + 6 * WIDTH * sizeof(float));

    // zero the flag region (graph node, stream-ordered before the kernel)
    hipMemsetAsync(flags, 0, 8 * NBLOCKS * sizeof(unsigned), stream);

    void* args[] = { (void*)&P, (void*)&x, (void*)&out, (void*)&slots, (void*)&flags };
    hipLaunchCooperativeKernel((const void*)mlp_fused_kernel,
                               dim3(NBLOCKS), dim3(TPB), args, 0, stream);
}